// Round 8
// baseline (4499.585 us; speedup 1.0000x reference)
//
#include <hip/hip_runtime.h>
#include <math.h>

#define NNODES 100000
#define NEDGES 800000
#define DIN    256
#define HID    64
#define NC     40
#define NL     2
#define EPSL   1e-5f
#define CHUNK  1024
#define NCHUNK ((NNODES + CHUNK - 1) / CHUNK)   // 98
#define NB128  ((NNODES + 127) / 128)           // 782
#define NB64   ((NNODES + 63) / 64)             // 1563
#define NKVB   512                              // kvs partial blocks
#define SLAB   8720                              // floats per block slab

__device__ __forceinline__ float wave_allsum(float v) {
#pragma unroll
  for (int off = 32; off > 0; off >>= 1) v += __shfl_xor(v, off);
  return v;
}

// ---------------- CSR build ----------------
__global__ void k_hist(const int* __restrict__ ei, int* __restrict__ deg) {
  for (int e = blockIdx.x * blockDim.x + threadIdx.x; e < NEDGES;
       e += gridDim.x * blockDim.x)
    atomicAdd(&deg[ei[NEDGES + e]], 1);
}

__global__ void k_scan1(const int* __restrict__ deg, int* __restrict__ csum) {
  __shared__ int sdata[256];
  int base = blockIdx.x * CHUNK;
  int s = 0;
  for (int t = threadIdx.x; t < CHUNK; t += 256) {
    int idx = base + t;
    if (idx < NNODES) s += deg[idx];
  }
  sdata[threadIdx.x] = s;
  __syncthreads();
  for (int off = 128; off > 0; off >>= 1) {
    if (threadIdx.x < off) sdata[threadIdx.x] += sdata[threadIdx.x + off];
    __syncthreads();
  }
  if (threadIdx.x == 0) csum[blockIdx.x] = sdata[0];
}

__global__ void k_scan2(const int* __restrict__ csum, int* __restrict__ cpref) {
  if (threadIdx.x == 0 && blockIdx.x == 0) {
    int run = 0;
    for (int i = 0; i < NCHUNK; ++i) { cpref[i] = run; run += csum[i]; }
  }
}

__global__ void k_scan3(const int* __restrict__ deg, const int* __restrict__ cpref,
                        int* __restrict__ offs) {
  __shared__ int bufA[CHUNK], bufB[CHUNK];
  int base = blockIdx.x * CHUNK;
  int orig[4];
#pragma unroll
  for (int i = 0; i < 4; ++i) {
    int t = threadIdx.x + i * 256;
    int idx = base + t;
    orig[i] = (idx < NNODES) ? deg[idx] : 0;
    bufA[t] = orig[i];
  }
  __syncthreads();
  int* src = bufA; int* dst = bufB;
  for (int off = 1; off < CHUNK; off <<= 1) {
#pragma unroll
    for (int i = 0; i < 4; ++i) {
      int t = threadIdx.x + i * 256;
      int vv = src[t];
      if (t >= off) vv += src[t - off];
      dst[t] = vv;
    }
    __syncthreads();
    int* tmp = src; src = dst; dst = tmp;
  }
  int cp = cpref[blockIdx.x];
#pragma unroll
  for (int i = 0; i < 4; ++i) {
    int t = threadIdx.x + i * 256;
    int idx = base + t;
    if (idx < NNODES) {
      offs[idx] = cp + src[t] - orig[i];
      if (idx == NNODES - 1) offs[NNODES] = cp + src[t];
    }
  }
}

__global__ void k_fill(const int* __restrict__ ei, const int* __restrict__ deg,
                       const int* __restrict__ offs, int* __restrict__ cursor,
                       int2* __restrict__ epack) {
  for (int e = blockIdx.x * blockDim.x + threadIdx.x; e < NEDGES;
       e += gridDim.x * blockDim.x) {
    int r = ei[e], c = ei[NEDGES + e];
    int pos = offs[c] + atomicAdd(&cursor[c], 1);
    int dc = deg[c], dr = deg[r];
    float w = (dr > 0)
        ? sqrtf(1.0f / (float)dc) * sqrtf(1.0f / (float)dr) : 0.0f;
    epack[pos] = make_int2(r, __float_as_int(w));
  }
}

// ------- fc0 + LN + relu (thread-owns-row, W staged in LDS) -------------
__global__ __launch_bounds__(128) void k_fc0(
    const float* __restrict__ x, const float* __restrict__ w,
    const float* __restrict__ b, const float* __restrict__ lnw_,
    const float* __restrict__ lnb_, float* __restrict__ h) {
  __shared__ float xs[32 * 132];   // k-major, padded stride
  __shared__ float ws[32 * 64];    // W chunk
  const int tid = threadIdx.x;
  const int base = blockIdx.x * 128;
  const int row = base + tid;
  const float4* x4 = (const float4*)x;
  float acc[64];
#pragma unroll
  for (int j = 0; j < 64; ++j) acc[j] = b[j];

  for (int c = 0; c < 8; ++c) {
    __syncthreads();
    // stage x chunk (transposed to k-major, padded)
#pragma unroll
    for (int i = 0; i < 8; ++i) {
      int r = i * 16 + (tid >> 3);
      int kq = tid & 7;
      int gr = base + r;
      float4 t = (gr < NNODES) ? x4[(size_t)gr * 64 + c * 8 + kq]
                               : make_float4(0.f, 0.f, 0.f, 0.f);
      xs[(kq * 4 + 0) * 132 + r] = t.x;
      xs[(kq * 4 + 1) * 132 + r] = t.y;
      xs[(kq * 4 + 2) * 132 + r] = t.z;
      xs[(kq * 4 + 3) * 132 + r] = t.w;
    }
    // stage W chunk (linear copy)
    {
      const float4* w4 = (const float4*)(w + c * 32 * 64);
      float4* s4 = (float4*)ws;
#pragma unroll
      for (int t = 0; t < 4; ++t) s4[tid + t * 128] = w4[tid + t * 128];
    }
    __syncthreads();
#pragma unroll 2
    for (int k = 0; k < 32; ++k) {
      float xv = xs[k * 132 + tid];
      const float* wr = &ws[k * 64];
#pragma unroll
      for (int j = 0; j < 64; ++j) acc[j] = fmaf(xv, wr[j], acc[j]);
    }
  }
  if (row < NNODES) {
    float mu = 0.f;
#pragma unroll
    for (int j = 0; j < 64; ++j) mu += acc[j];
    mu *= (1.0f / 64.0f);
    float var = 0.f;
#pragma unroll
    for (int j = 0; j < 64; ++j) { float d = acc[j] - mu; var = fmaf(d, d, var); }
    float inv = 1.0f / sqrtf(var * (1.0f / 64.0f) + EPSL);
    float4* h4 = (float4*)(h + (size_t)row * 64);
#pragma unroll
    for (int jj = 0; jj < 16; ++jj) {
      float4 o;
      o.x = fmaxf((acc[4*jj+0] - mu) * inv * lnw_[4*jj+0] + lnb_[4*jj+0], 0.f);
      o.y = fmaxf((acc[4*jj+1] - mu) * inv * lnw_[4*jj+1] + lnb_[4*jj+1], 0.f);
      o.z = fmaxf((acc[4*jj+2] - mu) * inv * lnw_[4*jj+2] + lnb_[4*jj+2], 0.f);
      o.w = fmaxf((acc[4*jj+3] - mu) * inv * lnw_[4*jj+3] + lnb_[4*jj+3], 0.f);
      h4[jj] = o;
    }
  }
}

// ------- QKV GEMM: W cols in VGPR, h rows uniform from LDS ---------------
// 192 threads = 3 waves (wave=mat); lane owns output cols 2*lane, 2*lane+1.
__global__ __launch_bounds__(192, 3) void k_qkv(
    const float* __restrict__ h,
    const float* __restrict__ Wq, const float* __restrict__ Wk,
    const float* __restrict__ Wv,
    const float* __restrict__ bq, const float* __restrict__ bk,
    const float* __restrict__ bv,
    float* __restrict__ q, float* __restrict__ kk, float* __restrict__ vv,
    float* __restrict__ red) {
  __shared__ float hs[128 * 64];   // row-major [128][64], 32 KB
  const int tid = threadIdx.x;
  const int wave = tid / 64;       // 0:q 1:k 2:v
  const int lane = tid & 63;
  const int base = blockIdx.x * 128;
  const int nrow = NNODES - base;  // rows valid in this block
  // stage h rows (straight linear copy, coalesced, conflict-free)
  {
    const float4* h4 = (const float4*)(h + (size_t)base * 64);
    float4* s4 = (float4*)hs;
    for (int t = tid; t < 2048; t += 192) {
      float4 val = make_float4(0.f, 0.f, 0.f, 0.f);
      if ((t >> 4) < nrow) val = h4[t];
      s4[t] = val;
    }
  }
  const float* W = (wave == 0) ? Wq : (wave == 1) ? Wk : Wv;
  const float* B = (wave == 0) ? bq : (wave == 1) ? bk : bv;
  float* outp    = (wave == 0) ? q  : (wave == 1) ? kk : vv;
  const int j0 = lane * 2;
  float w0[64], w1[64];
#pragma unroll
  for (int t = 0; t < 64; ++t) {
    float2 wv_ = *(const float2*)(W + t * 128 + j0);
    w0[t] = wv_.x; w1[t] = wv_.y;
  }
  const float b0 = B[j0], b1 = B[j0 + 1];
  __syncthreads();
  float sq = 0.f;
  for (int r = 0; r < 128; r += 2) {
    float a0 = b0, a1 = b1, c0 = b0, c1 = b1;
#pragma unroll
    for (int t = 0; t < 16; ++t) {
      float4 ha = *(const float4*)&hs[r * 64 + t * 4];
      float4 hb = *(const float4*)&hs[(r + 1) * 64 + t * 4];
      a0 = fmaf(ha.x, w0[4*t+0], a0); a1 = fmaf(ha.x, w1[4*t+0], a1);
      a0 = fmaf(ha.y, w0[4*t+1], a0); a1 = fmaf(ha.y, w1[4*t+1], a1);
      a0 = fmaf(ha.z, w0[4*t+2], a0); a1 = fmaf(ha.z, w1[4*t+2], a1);
      a0 = fmaf(ha.w, w0[4*t+3], a0); a1 = fmaf(ha.w, w1[4*t+3], a1);
      c0 = fmaf(hb.x, w0[4*t+0], c0); c1 = fmaf(hb.x, w1[4*t+0], c1);
      c0 = fmaf(hb.y, w0[4*t+1], c0); c1 = fmaf(hb.y, w1[4*t+1], c1);
      c0 = fmaf(hb.z, w0[4*t+2], c0); c1 = fmaf(hb.z, w1[4*t+2], c1);
      c0 = fmaf(hb.w, w0[4*t+3], c0); c1 = fmaf(hb.w, w1[4*t+3], c1);
    }
    if (r < nrow) {
      *(float2*)(outp + (size_t)(base + r) * 128 + j0) = make_float2(a0, a1);
      if (wave == 0) { sq = fmaf(a0, a0, sq); sq = fmaf(a1, a1, sq); }
    }
    if (r + 1 < nrow) {
      *(float2*)(outp + (size_t)(base + r + 1) * 128 + j0) = make_float2(c0, c1);
      if (wave == 0) { sq = fmaf(c0, c0, sq); sq = fmaf(c1, c1, sq); }
    }
  }
  if (wave == 0) {
    float t = wave_allsum(sq);
    if (lane == 0) atomicAdd(&red[0], t);
  }
}

// ------- KVS partials (no atomics) + ksum/vsum/sum(k^2) + vh -------------
__global__ __launch_bounds__(256) void k_kvs(
    const float* __restrict__ k, const float* __restrict__ v,
    float* __restrict__ vh, float* __restrict__ slab) {
  __shared__ float kc[64 * 128], vc[64 * 128];
  __shared__ float sred[4];
  const int tid = threadIdx.x;
  const int hh = tid >> 7;
  const int t2 = tid & 127;
  const int mt = t2 >> 3;
  const int dt = t2 & 7;
  float acc[4][8];
#pragma unroll
  for (int a = 0; a < 4; ++a)
#pragma unroll
    for (int bq_ = 0; bq_ < 8; ++bq_) acc[a][bq_] = 0.f;
  float ksl = 0.f, vsl = 0.f, sqk = 0.f;
  const float4* k4 = (const float4*)k;
  const float4* v4 = (const float4*)v;

  for (int base = blockIdx.x * 64; base < NNODES; base += NKVB * 64) {
    if (base + 64 <= NNODES) {
      for (int t = tid; t < 2048; t += 256) {
        *(float4*)&kc[t * 4] = k4[(size_t)base * 32 + t];
        *(float4*)&vc[t * 4] = v4[(size_t)base * 32 + t];
      }
    } else {
      for (int t = tid; t < 2048; t += 256) {
        int node = base + (t >> 5);
        int c4 = t & 31;
        float4 kk4 = make_float4(0.f, 0.f, 0.f, 0.f), vv4 = kk4;
        if (node < NNODES) {
          kk4 = k4[(size_t)node * 32 + c4];
          vv4 = v4[(size_t)node * 32 + c4];
        }
        *(float4*)&kc[t * 4] = kk4;
        *(float4*)&vc[t * 4] = vv4;
      }
    }
    __syncthreads();
#pragma unroll 4
    for (int n = hh * 32; n < hh * 32 + 32; ++n) {
      float kv_ = kc[n * 128 + t2], vv_ = vc[n * 128 + t2];
      ksl += kv_; sqk = fmaf(kv_, kv_, sqk); vsl += vv_;
    }
    for (int t = tid; t < 4096; t += 256) {
      int n = t >> 6, d = t & 63;
      if (base + n < NNODES)
        vh[(size_t)(base + n) * 64 + d] =
            0.5f * (vc[n * 128 + d] + vc[n * 128 + 64 + d]);
    }
#pragma unroll 8
    for (int nn = 0; nn < 64; ++nn) {
      const float4 kk = *(const float4*)&kc[nn * 128 + hh * 64 + mt * 4];
      const float4 va = *(const float4*)&vc[nn * 128 + hh * 64 + dt * 8];
      const float4 vb = *(const float4*)&vc[nn * 128 + hh * 64 + dt * 8 + 4];
#pragma unroll
      for (int a = 0; a < 4; ++a) {
        float kx = (a == 0) ? kk.x : (a == 1) ? kk.y : (a == 2) ? kk.z : kk.w;
        acc[a][0] = fmaf(kx, va.x, acc[a][0]);
        acc[a][1] = fmaf(kx, va.y, acc[a][1]);
        acc[a][2] = fmaf(kx, va.z, acc[a][2]);
        acc[a][3] = fmaf(kx, va.w, acc[a][3]);
        acc[a][4] = fmaf(kx, vb.x, acc[a][4]);
        acc[a][5] = fmaf(kx, vb.y, acc[a][5]);
        acc[a][6] = fmaf(kx, vb.z, acc[a][6]);
        acc[a][7] = fmaf(kx, vb.w, acc[a][7]);
      }
    }
    __syncthreads();
  }
  float* sb = slab + (size_t)blockIdx.x * SLAB;
#pragma unroll
  for (int a = 0; a < 4; ++a) {
    *(float4*)&sb[hh * 4096 + (mt * 4 + a) * 64 + dt * 8] =
        make_float4(acc[a][0], acc[a][1], acc[a][2], acc[a][3]);
    *(float4*)&sb[hh * 4096 + (mt * 4 + a) * 64 + dt * 8 + 4] =
        make_float4(acc[a][4], acc[a][5], acc[a][6], acc[a][7]);
  }
  sb[8192 + tid] = ksl;
  sb[8448 + tid] = vsl;
  float ws = wave_allsum(sqk);
  if ((tid & 63) == 0) sred[tid >> 6] = ws;
  __syncthreads();
  if (tid == 0) sb[8704] = sred[0] + sred[1] + sred[2] + sred[3];
}

// ---------------- reduce slabs -> red ------------------------------------
__global__ __launch_bounds__(256) void k_red(
    const float* __restrict__ slab, float* __restrict__ red) {
  int idx = blockIdx.x * 256 + threadIdx.x;
  if (idx < 8192) {
    float s = 0.f;
#pragma unroll 4
    for (int b = 0; b < NKVB; ++b) s += slab[(size_t)b * SLAB + idx];
    red[258 + idx] = s;
  } else if (idx < 8320) {
    int r = idx - 8192;
    float s = 0.f;
#pragma unroll 4
    for (int b = 0; b < NKVB; ++b)
      s += slab[(size_t)b * SLAB + 8192 + r] +
           slab[(size_t)b * SLAB + 8192 + 128 + r];
    red[2 + r] = s;
  } else if (idx < 8448) {
    int r = idx - 8320;
    float s = 0.f;
#pragma unroll 4
    for (int b = 0; b < NKVB; ++b)
      s += slab[(size_t)b * SLAB + 8448 + r] +
           slab[(size_t)b * SLAB + 8448 + 128 + r];
    red[130 + r] = s;
  } else if (idx == 8448) {
    float s = 0.f;
#pragma unroll 4
    for (int b = 0; b < NKVB; ++b) s += slab[(size_t)b * SLAB + 8704];
    red[1] = s;
  }
}

// ------- attention: KVS cols in VGPR (both heads), q rows uniform --------
// 128 threads = 2 waves; block handles 64 rows; lane owns output col d=lane.
__global__ __launch_bounds__(128, 3) void k_attn(
    const float* __restrict__ q, const float* __restrict__ red,
    float* __restrict__ attnm) {
  __shared__ float qs[64 * 128];   // phase A: KVS; phase B: q rows (32 KB)
  const int tid = threadIdx.x;
  const int lane = tid & 63;
  const int wave = tid >> 6;
  const int base = blockIdx.x * 64;
  const int nrow = NNODES - base;
  // phase A: stage KVS, pull own columns into VGPRs
  {
    const float4* r4 = (const float4*)(red + 258);
    float4* s4 = (float4*)qs;
    for (int t = tid; t < 2048; t += 128) s4[t] = r4[t];
  }
  __syncthreads();
  float kvA[64], kvB[64];
#pragma unroll
  for (int m = 0; m < 64; ++m) {
    kvA[m] = qs[m * 64 + lane];          // head0 KVS[m][d]
    kvB[m] = qs[4096 + m * 64 + lane];   // head1
  }
  const float ksA = red[2 + lane],   ksB = red[2 + 64 + lane];
  const float vsA = red[130 + lane], vsB = red[130 + 64 + lane];
  const float inv_qk = (1.0f / sqrtf(red[0])) * (1.0f / sqrtf(red[1]));
  __syncthreads();
  // phase B: stage q rows (linear copy)
  {
    const float4* q4 = (const float4*)(q + (size_t)base * 128);
    float4* s4 = (float4*)qs;
    for (int t = tid; t < 2048; t += 128) {
      float4 val = make_float4(0.f, 0.f, 0.f, 0.f);
      if ((t >> 5) < nrow) val = q4[t];
      s4[t] = val;
    }
  }
  __syncthreads();
  const int r0 = wave * 32;
  for (int r = r0; r < r0 + 32; r += 2) {
    float a0 = 0.f, a1 = 0.f, c0 = 0.f, c1 = 0.f;
#pragma unroll
    for (int t = 0; t < 16; ++t) {
      float4 qa = *(const float4*)&qs[r * 128 + t * 4];
      float4 qb = *(const float4*)&qs[r * 128 + 64 + t * 4];
      float4 ra = *(const float4*)&qs[(r + 1) * 128 + t * 4];
      float4 rb = *(const float4*)&qs[(r + 1) * 128 + 64 + t * 4];
      a0 = fmaf(qa.x, kvA[4*t+0], a0); a1 = fmaf(qb.x, kvB[4*t+0], a1);
      a0 = fmaf(qa.y, kvA[4*t+1], a0); a1 = fmaf(qb.y, kvB[4*t+1], a1);
      a0 = fmaf(qa.z, kvA[4*t+2], a0); a1 = fmaf(qb.z, kvB[4*t+2], a1);
      a0 = fmaf(qa.w, kvA[4*t+3], a0); a1 = fmaf(qb.w, kvB[4*t+3], a1);
      c0 = fmaf(ra.x, kvA[4*t+0], c0); c1 = fmaf(rb.x, kvB[4*t+0], c1);
      c0 = fmaf(ra.y, kvA[4*t+1], c0); c1 = fmaf(rb.y, kvB[4*t+1], c1);
      c0 = fmaf(ra.z, kvA[4*t+2], c0); c1 = fmaf(rb.z, kvB[4*t+2], c1);
      c0 = fmaf(ra.w, kvA[4*t+3], c0); c1 = fmaf(rb.w, kvB[4*t+3], c1);
    }
    // denominators (per-row reductions across lanes)
    float d0a = wave_allsum(qs[r * 128 + lane] * ksA);
    float d1a = wave_allsum(qs[r * 128 + 64 + lane] * ksB);
    float d0b = wave_allsum(qs[(r + 1) * 128 + lane] * ksA);
    float d1b = wave_allsum(qs[(r + 1) * 128 + 64 + lane] * ksB);
    float t0 = (a0 * inv_qk + vsA) / (d0a * inv_qk + (float)NNODES);
    float t1 = (a1 * inv_qk + vsB) / (d1a * inv_qk + (float)NNODES);
    float u0 = (c0 * inv_qk + vsA) / (d0b * inv_qk + (float)NNODES);
    float u1 = (c1 * inv_qk + vsB) / (d1b * inv_qk + (float)NNODES);
    if (r < nrow)     attnm[(size_t)(base + r) * 64 + lane] = 0.5f * (t0 + t1);
    if (r + 1 < nrow) attnm[(size_t)(base + r + 1) * 64 + lane] = 0.5f * (u0 + u1);
  }
}

// ---------------- GCN gather + mean/residual + LN (wave-per-node) --------
__global__ __launch_bounds__(256) void k_gcnln(
    const float* __restrict__ attnm, const float* __restrict__ vh,
    const float* __restrict__ prev, const int* __restrict__ offs,
    const int2* __restrict__ epack,
    const float* __restrict__ lnw_, const float* __restrict__ lnb_,
    float* __restrict__ hout) {
  const int wave = threadIdx.x >> 6, lane = threadIdx.x & 63;
  const float lw = lnw_[lane], lb = lnb_[lane];
  for (int node = blockIdx.x * 4 + wave; node < NNODES; node += gridDim.x * 4) {
    float g = 0.f;
    int s = offs[node], e = offs[node + 1];
    int i = s;
    for (; i + 1 < e; i += 2) {
      int2 e0 = epack[i], e1 = epack[i + 1];
      float v0 = vh[(size_t)e0.x * 64 + lane];
      float v1 = vh[(size_t)e1.x * 64 + lane];
      g = fmaf(__int_as_float(e0.y), v0, g);
      g = fmaf(__int_as_float(e1.y), v1, g);
    }
    if (i < e) {
      int2 e0 = epack[i];
      g = fmaf(__int_as_float(e0.y), vh[(size_t)e0.x * 64 + lane], g);
    }
    float om = attnm[(size_t)node * 64 + lane] + g;
    float pre = 0.5f * om + 0.5f * prev[(size_t)node * 64 + lane];
    float mu = wave_allsum(pre) * (1.0f / 64.0f);
    float d = pre - mu;
    float var = wave_allsum(d * d) * (1.0f / 64.0f);
    hout[(size_t)node * 64 + lane] = d * (1.0f / sqrtf(var + EPSL)) * lw + lb;
  }
}

// ---------------- final classifier (thread-owns-row, W in LDS) -----------
__global__ __launch_bounds__(128) void k_final(
    const float* __restrict__ h, const float* __restrict__ w,
    const float* __restrict__ b, float* __restrict__ out) {
  __shared__ float hs[64 * 132];
  __shared__ float wl[HID * NC];   // 10 KB
  const int tid = threadIdx.x;
  const int base = blockIdx.x * 128;
  const int row = base + tid;
  {
    const float4* w4 = (const float4*)w;
    float4* s4 = (float4*)wl;
    for (int t = tid; t < 640; t += 128) s4[t] = w4[t];
  }
  const float4* h4 = (const float4*)h;
#pragma unroll
  for (int i = 0; i < 16; ++i) {
    int r = i * 8 + (tid >> 4);
    int kq = tid & 15;
    int gr = base + r;
    float4 t = (gr < NNODES) ? h4[(size_t)gr * 16 + kq]
                             : make_float4(0.f, 0.f, 0.f, 0.f);
    hs[(kq * 4 + 0) * 132 + r] = t.x;
    hs[(kq * 4 + 1) * 132 + r] = t.y;
    hs[(kq * 4 + 2) * 132 + r] = t.z;
    hs[(kq * 4 + 3) * 132 + r] = t.w;
  }
  __syncthreads();
  float acc[NC];
#pragma unroll
  for (int j = 0; j < NC; ++j) acc[j] = b[j];
#pragma unroll 2
  for (int k = 0; k < 64; ++k) {
    float xv = hs[k * 132 + tid];
    const float* wr = &wl[k * NC];
#pragma unroll
    for (int j = 0; j < NC; ++j) acc[j] = fmaf(xv, wr[j], acc[j]);
  }
  if (row < NNODES) {
    float4* o4 = (float4*)(out + (size_t)row * NC);
#pragma unroll
    for (int jj = 0; jj < NC / 4; ++jj)
      o4[jj] = make_float4(acc[4*jj], acc[4*jj+1], acc[4*jj+2], acc[4*jj+3]);
  }
}

extern "C" void kernel_launch(void* const* d_in, const int* in_sizes, int n_in,
                              void* d_out, int out_size, void* d_ws,
                              size_t ws_size, hipStream_t stream) {
  const float* x     = (const float*)d_in[0];
  const int*   ei    = (const int*)d_in[1];
  const float* fc0_w = (const float*)d_in[2];
  const float* fc0_b = (const float*)d_in[3];
  const float* ln_w  = (const float*)d_in[4];
  const float* ln_b  = (const float*)d_in[5];
  const float* Wq    = (const float*)d_in[6];
  const float* Wk    = (const float*)d_in[7];
  const float* Wv    = (const float*)d_in[8];
  const float* bq    = (const float*)d_in[9];
  const float* bk    = (const float*)d_in[10];
  const float* bv    = (const float*)d_in[11];
  const float* fco_w = (const float*)d_in[12];
  const float* fco_b = (const float*)d_in[13];
  float* out = (float*)d_out;

  char* p = (char*)d_ws;
  auto alloc = [&](size_t bytes) {
    char* r = p;
    p += (bytes + 255) & ~(size_t)255;
    return r;
  };
  float* q    = (float*)alloc(sizeof(float) * (size_t)NNODES * 128);
  float* kbuf = (float*)alloc(sizeof(float) * (size_t)NNODES * 128);
  float* vbuf = (float*)alloc(sizeof(float) * (size_t)NNODES * 128);
  float* hA   = (float*)alloc(sizeof(float) * (size_t)NNODES * HID);
  float* hB   = (float*)alloc(sizeof(float) * (size_t)NNODES * HID);
  float* vh   = (float*)alloc(sizeof(float) * (size_t)NNODES * HID);
  float* red  = (float*)alloc(sizeof(float) * 8704);
  float* slab = (float*)alloc(sizeof(float) * (size_t)NKVB * SLAB);
  int* deg    = (int*)alloc(sizeof(int) * NNODES);
  int* offs   = (int*)alloc(sizeof(int) * (NNODES + 1));
  int* cursor = (int*)alloc(sizeof(int) * NNODES);
  int2* epack = (int2*)alloc(sizeof(int2) * NEDGES);
  int* csum   = (int*)alloc(sizeof(int) * 128);
  int* cpref  = (int*)alloc(sizeof(int) * 128);
  float* attnm = kbuf;   // kbuf dead after k_kvs; reuse as attnm

  // ---- CSR build ----
  hipMemsetAsync(deg, 0, sizeof(int) * NNODES, stream);
  hipMemsetAsync(cursor, 0, sizeof(int) * NNODES, stream);
  k_hist<<<1024, 256, 0, stream>>>(ei, deg);
  k_scan1<<<NCHUNK, 256, 0, stream>>>(deg, csum);
  k_scan2<<<1, 64, 0, stream>>>(csum, cpref);
  k_scan3<<<NCHUNK, 256, 0, stream>>>(deg, cpref, offs);
  k_fill<<<1024, 256, 0, stream>>>(ei, deg, offs, cursor, epack);

  // ---- input projection ----
  k_fc0<<<NB128, 128, 0, stream>>>(x, fc0_w, fc0_b, ln_w, ln_b, hA);

  float* hin = hA;
  float* hot = hB;
  for (int l = 0; l < NL; ++l) {
    hipMemsetAsync(red, 0, sizeof(float) * 2, stream);
    k_qkv<<<NB128, 192, 0, stream>>>(hin,
        Wq + (size_t)l * HID * 128, Wk + (size_t)l * HID * 128,
        Wv + (size_t)l * HID * 128,
        bq + (size_t)l * 128, bk + (size_t)l * 128, bv + (size_t)l * 128,
        q, kbuf, vbuf, red);
    k_kvs<<<NKVB, 256, 0, stream>>>(kbuf, vbuf, vh, slab);
    k_red<<<34, 256, 0, stream>>>(slab, red);
    k_attn<<<NB64, 128, 0, stream>>>(q, red, attnm);
    k_gcnln<<<2048, 256, 0, stream>>>(attnm, vh, hin, offs, epack,
        ln_w + (size_t)(l + 1) * HID, ln_b + (size_t)(l + 1) * HID, hot);
    float* tmp = hin; hin = hot; hot = tmp;
  }

  k_final<<<NB128, 128, 0, stream>>>(hin, fco_w, fco_b, out);
}